// Round 8
// baseline (336.976 us; speedup 1.0000x reference)
//
#include <hip/hip_runtime.h>

typedef unsigned short u16;
typedef __bf16 bf16x8 __attribute__((ext_vector_type(8)));
typedef short s16x4 __attribute__((ext_vector_type(4)));
typedef float f32x4 __attribute__((ext_vector_type(4)));

// ---------- helpers ----------
__device__ __forceinline__ u16 f2bf(float f) {
  unsigned u = __float_as_uint(f);
  unsigned r = u + 0x7fffu + ((u >> 16) & 1u);   // RNE
  return (u16)(r >> 16);
}

// two f32 -> packed bf16 dword in ONE instruction (low16 = a, high16 = b)
__device__ __forceinline__ unsigned cvt_pk(float a, float b) {
  unsigned r;
  asm("v_cvt_pk_bf16_f32 %0, %1, %2" : "=v"(r) : "v"(a), "v"(b));
  return r;
}

// exp2 via the builtin (raw v_exp_f32 WITH correct TRANS hazard modeling).
// R4 lesson: inline-asm v_exp_f32 loses the TRANS hazard nops -> NaN.
// R5 lesson: this swap alone was -30us on flash (exp2f lowers to OCML wrapper).
#if __has_builtin(__builtin_amdgcn_exp2f)
#define EXP2(x) __builtin_amdgcn_exp2f(x)
#else
#define EXP2(x) exp2f(x)
#endif

__device__ __forceinline__ void async_cp16(const void* g, void* l) {
  __builtin_amdgcn_global_load_lds((__attribute__((address_space(1))) void*)g,
                                   (__attribute__((address_space(3))) void*)l,
                                   16, 0, 0);
}

#define MFMA32(a, b, c) __builtin_amdgcn_mfma_f32_16x16x32_bf16(a, b, c, 0, 0, 0)

#if __has_builtin(__builtin_amdgcn_mfma_f32_16x16x16bf16_1k)
#define MFMA16(a, b, c) __builtin_amdgcn_mfma_f32_16x16x16bf16_1k(a, b, c, 0, 0, 0)
#else
__device__ __forceinline__ f32x4 mfma16_fb(s16x4 a, s16x4 b, f32x4 c) {
  asm("v_mfma_f32_16x16x16_bf16 %0, %1, %2, %0" : "+v"(c) : "v"(a), "v"(b));
  return c;
}
#define MFMA16(a, b, c) mfma16_fb(a, b, c)
#endif

// ---------- fused LayerNorm + bf16 cast (x and ctx in one dispatch) ----------
__global__ __launch_bounds__(256)
void ln_cast2(const float* __restrict__ X0, const float* __restrict__ X1,
              const float* __restrict__ W0, const float* __restrict__ B0,
              const float* __restrict__ W1, const float* __restrict__ B1,
              u16* __restrict__ Y0, u16* __restrict__ Y1) {
  __shared__ float red[8];
  const int blk = blockIdx.x, t = threadIdx.x;
  const int sel = blk >> 13;            // 0: x->qin, 1: ctx->kvin
  const int row = blk & 8191;
  const float* X = sel ? X1 : X0;
  const float* W = sel ? W1 : W0;
  const float* Bv = sel ? B1 : B0;
  u16* Y = sel ? Y1 : Y0;
  const int wave = t >> 6, lane = t & 63;
  const float4 v = ((const float4*)(X + (size_t)row * 1024))[t];
  float s  = v.x + v.y + v.z + v.w;
  float ss = v.x*v.x + v.y*v.y + v.z*v.z + v.w*v.w;
#pragma unroll
  for (int m = 32; m; m >>= 1) { s += __shfl_xor(s, m, 64); ss += __shfl_xor(ss, m, 64); }
  if (lane == 0) { red[wave] = s; red[4 + wave] = ss; }
  __syncthreads();
  float S  = red[0] + red[1] + red[2] + red[3];
  float SS = red[4] + red[5] + red[6] + red[7];
  float mu  = S * (1.0f / 1024.0f);
  float var = SS * (1.0f / 1024.0f) - mu * mu;
  float rstd = rsqrtf(var + 1e-5f);
  const float4 wv = ((const float4*)W)[t];
  const float4 bv = ((const float4*)Bv)[t];
  ushort4 o;
  o.x = f2bf((v.x - mu) * rstd * wv.x + bv.x);
  o.y = f2bf((v.y - mu) * rstd * wv.y + bv.y);
  o.z = f2bf((v.z - mu) * rstd * wv.z + bv.z);
  o.w = f2bf((v.w - mu) * rstd * wv.w + bv.w);
  ((ushort4*)(Y + (size_t)row * 1024))[t] = o;
}

// ---------- weight transpose + cast: all four W[K][N] f32 -> WT[N][K] bf16 ----------
__global__ __launch_bounds__(256)
void wtrans4(const float* __restrict__ Wq, const float* __restrict__ Wk,
             const float* __restrict__ Wv, const float* __restrict__ Wo,
             u16* __restrict__ WqT, u16* __restrict__ WkT,
             u16* __restrict__ WvT, u16* __restrict__ WoT) {
  __shared__ float t[64][65];
  const int z = blockIdx.z;
  const float* W = z == 0 ? Wq : (z == 1 ? Wk : (z == 2 ? Wv : Wo));
  u16* WT = z == 0 ? WqT : (z == 1 ? WkT : (z == 2 ? WvT : WoT));
  const int k0 = blockIdx.y * 64, n0 = blockIdx.x * 64;
  const int lr = threadIdx.x >> 4, lc = threadIdx.x & 15;
#pragma unroll
  for (int r = 0; r < 4; ++r) {
    int row = r * 16 + lr;
    float4 v = *(const float4*)(W + (size_t)(k0 + row) * 1024 + n0 + lc * 4);
    t[row][lc*4+0] = v.x; t[row][lc*4+1] = v.y; t[row][lc*4+2] = v.z; t[row][lc*4+3] = v.w;
  }
  __syncthreads();
#pragma unroll
  for (int r = 0; r < 4; ++r) {
    int n = r * 16 + lr;
    ushort4 o;
    o.x = f2bf(t[lc*4+0][n]); o.y = f2bf(t[lc*4+1][n]);
    o.z = f2bf(t[lc*4+2][n]); o.w = f2bf(t[lc*4+3][n]);
    *(ushort4*)(WT + (size_t)(n0 + n) * 1024 + k0 + lc * 4) = o;
  }
}

// ---------- fused Q/K/V projection GEMM (m97 structure, 1536 blocks) ----------
// z=0: qbf = l2n(qin x WqT, scaled);  z=1: kbf = l2n(kvin x WkT);
// z=2: vT = (kvin x WvT)^T directly as bf16 [b][h][d][kk] (vtrans fused:
//       saves 32MB f32 write + 32MB read + the vtrans kernel).
__global__ __launch_bounds__(256, 2)
void gemm_qkv(const u16* __restrict__ qin, const u16* __restrict__ kvin,
              const u16* __restrict__ WqT, const u16* __restrict__ WkT,
              const u16* __restrict__ WvT,
              u16* __restrict__ qbf, u16* __restrict__ kbf,
              u16* __restrict__ vT, const float* __restrict__ taup) {
  __shared__ __align__(16) u16 shbuf[128 * 128];   // As | Bs staging; reused as transpose tile
  u16* As = shbuf;                                  // 128*64
  u16* Bs = shbuf + 128 * 64;                       // 128*64
  const int z = blockIdx.z;
  const u16* A  = z == 0 ? qin : kvin;
  const u16* Bt = z == 0 ? WqT : (z == 1 ? WkT : WvT);
  const int tid = threadIdx.x;
  const int wave = tid >> 6, lane = tid & 63;
  const int quad = lane >> 4, l15 = lane & 15;
  const int m0 = blockIdx.y * 128, n0 = blockIdx.x * 128;
  const int wm = (wave >> 1) * 64, wn = (wave & 1) * 64;
  const int srow = lane >> 3, scol = (lane & 7) * 8;
  const int K = 1024, N = 1024;

  const f32x4 fz = {0.f, 0.f, 0.f, 0.f};
  f32x4 acc[4][4];
#pragma unroll
  for (int i = 0; i < 4; ++i)
#pragma unroll
    for (int j = 0; j < 4; ++j) acc[i][j] = fz;

  for (int kt = 0; kt < K; kt += 64) {
    __syncthreads();
#pragma unroll
    for (int r = 0; r < 4; ++r) {
      const int c = r * 4 + wave;
      const int row = c * 8 + srow;
      async_cp16(A  + (size_t)(m0 + row) * K + kt + scol, (char*)As + c * 1024);
      async_cp16(Bt + (size_t)(n0 + row) * K + kt + scol, (char*)Bs + c * 1024);
    }
    __syncthreads();
#pragma unroll
    for (int ks = 0; ks < 2; ++ks) {
      bf16x8 af[4], bfr[4];
#pragma unroll
      for (int i = 0; i < 4; ++i)
        af[i] = *(const bf16x8*)(const void*)(As + (wm + i * 16 + l15) * 64 + ks * 32 + quad * 8);
#pragma unroll
      for (int j = 0; j < 4; ++j)
        bfr[j] = *(const bf16x8*)(const void*)(Bs + (wn + j * 16 + l15) * 64 + ks * 32 + quad * 8);
#pragma unroll
      for (int i = 0; i < 4; ++i)
#pragma unroll
        for (int j = 0; j < 4; ++j)
          acc[i][j] = MFMA32(af[i], bfr[j], acc[i][j]);
    }
  }

  if (z < 2) {
    // per-head l2norm epilogue -> bf16 (wave strip == one head)
    const float tsc = z == 0 ? 1.44269504f / (taup[0] + 1e-6f) : 1.0f;
    u16* Y = z == 0 ? qbf : kbf;
#pragma unroll
    for (int i = 0; i < 4; ++i)
#pragma unroll
      for (int e = 0; e < 4; ++e) {
        float ss = 0.f;
#pragma unroll
        for (int j = 0; j < 4; ++j) ss = fmaf(acc[i][j][e], acc[i][j][e], ss);
        ss += __shfl_xor(ss, 1, 64); ss += __shfl_xor(ss, 2, 64);
        ss += __shfl_xor(ss, 4, 64); ss += __shfl_xor(ss, 8, 64);
        float sc = tsc / fmaxf(sqrtf(ss), 1e-12f);
        int row = m0 + wm + i * 16 + quad * 4 + e;
#pragma unroll
        for (int j = 0; j < 4; ++j)
          Y[(size_t)row * N + n0 + wn + j * 16 + l15] = f2bf(acc[i][j][e] * sc);
      }
  } else {
    // fused V-transpose epilogue: acc[kk_local][col_local] -> vT[b][h][d][kk] bf16.
    // LDS tile T[col][kk], XOR bank-swizzle: byte = col*256 + ((kk*2)^((col&7)<<4)).
    __syncthreads();                                   // As/Bs reads all done
    u16* T = shbuf;
#pragma unroll
    for (int i = 0; i < 4; ++i)
#pragma unroll
      for (int j = 0; j < 4; ++j) {
        int col = wn + j * 16 + l15;
        int kkb = (wm + i * 16 + quad * 4) * 2;        // byte offset of 4 contiguous kk
        union { unsigned u[2]; s16x4 s; } pk;
        pk.u[0] = cvt_pk(acc[i][j][0], acc[i][j][1]);
        pk.u[1] = cvt_pk(acc[i][j][2], acc[i][j][3]);
        *(s16x4*)(void*)((char*)T + col * 256 + (kkb ^ ((col & 7) << 4))) = pk.s;
      }
    __syncthreads();
    // coalesced write: 2 threads per col, each streams 64 kk (8 x int4)
    const int bb = m0 >> 11, kk0 = m0 & 2047;
    const int col = tid >> 1, half = tid & 1;
    const int hh = (n0 + col) >> 6, d = (n0 + col) & 63;
    u16* dst = vT + ((size_t)(bb * 16 + hh) * 64 + d) * 2048 + kk0 + half * 64;
#pragma unroll
    for (int p = 0; p < 8; ++p) {
      int kkb = (half * 64 + p * 8) * 2;
      int4 v = *(const int4*)(const void*)((const char*)T + col * 256 + (kkb ^ ((col & 7) << 4)));
      *(int4*)(dst + p * 8) = v;
    }
  }
}

// ---------- GEMM: C[M][N] f32 = A[M][K] bf16 x BT[N][K] bf16 (m97 structure) ----------
__global__ __launch_bounds__(256, 2)
void gemm_bt(const u16* __restrict__ A, const u16* __restrict__ Bt,
             float* __restrict__ C, int M, int N, int K) {
  __shared__ __align__(16) u16 As[128 * 64];
  __shared__ __align__(16) u16 Bs[128 * 64];
  const int tid = threadIdx.x;
  const int wave = tid >> 6, lane = tid & 63;
  const int quad = lane >> 4, l15 = lane & 15;
  const int m0 = blockIdx.y * 128, n0 = blockIdx.x * 128;
  const int wm = (wave >> 1) * 64, wn = (wave & 1) * 64;
  const int srow = lane >> 3, scol = (lane & 7) * 8;

  const f32x4 fz = {0.f, 0.f, 0.f, 0.f};
  f32x4 acc[4][4];
#pragma unroll
  for (int i = 0; i < 4; ++i)
#pragma unroll
    for (int j = 0; j < 4; ++j) acc[i][j] = fz;

  for (int kt = 0; kt < K; kt += 64) {
    __syncthreads();
#pragma unroll
    for (int r = 0; r < 4; ++r) {
      const int c = r * 4 + wave;
      const int row = c * 8 + srow;
      async_cp16(A  + (size_t)(m0 + row) * K + kt + scol, (char*)As + c * 1024);
      async_cp16(Bt + (size_t)(n0 + row) * K + kt + scol, (char*)Bs + c * 1024);
    }
    __syncthreads();
#pragma unroll
    for (int ks = 0; ks < 2; ++ks) {
      bf16x8 af[4], bfr[4];
#pragma unroll
      for (int i = 0; i < 4; ++i)
        af[i] = *(const bf16x8*)(const void*)(As + (wm + i * 16 + l15) * 64 + ks * 32 + quad * 8);
#pragma unroll
      for (int j = 0; j < 4; ++j)
        bfr[j] = *(const bf16x8*)(const void*)(Bs + (wn + j * 16 + l15) * 64 + ks * 32 + quad * 8);
#pragma unroll
      for (int i = 0; i < 4; ++i)
#pragma unroll
        for (int j = 0; j < 4; ++j)
          acc[i][j] = MFMA32(af[i], bfr[j], acc[i][j]);
    }
  }
#pragma unroll
  for (int i = 0; i < 4; ++i)
#pragma unroll
    for (int j = 0; j < 4; ++j)
#pragma unroll
      for (int e = 0; e < 4; ++e) {
        int row = m0 + wm + i * 16 + quad * 4 + e;
        int col = n0 + wn + j * 16 + l15;
        C[(size_t)row * N + col] = acc[i][j][e];
      }
}

// ---------- flash attention v10 (validated R7: 104us, issue-bound) ----------
__global__ __launch_bounds__(256, 2)
void flash_attn10(const u16* __restrict__ Qb, const u16* __restrict__ Kb,
                  const u16* __restrict__ Vt, const int* __restrict__ mask,
                  u16* __restrict__ Ob) {
  // union region: Q staging (128x64 = 16 KB) OVERLAPS K/V dbuf (4 x 8 KB):
  //   bytes [0,8192)=Ks0  [8192,16384)=Ks1  [16384,24576)=Vs0  [24576,32768)=Vs1
  // epilogue strips (4 KB/wave) also land here after the final barrier.
  __shared__ __align__(16) u16 SH[16384];       // 32 KB union
  __shared__ __align__(16) float Msf[2048];     // 8 KB mask bias f32: 0 or -3e38
  const int tid = threadIdx.x, w = tid >> 6, lane = tid & 63;
  const int quad = lane >> 4, l15 = lane & 15;
  const int b = blockIdx.z, h = blockIdx.y, q0 = blockIdx.x * 128;
  const int srow = lane >> 3;
  const int scolX = ((lane & 7) ^ srow) * 8;    // swizzled source column (u16 units)
  const int fsw = ((l15 & 7) << 4);             // read-side XOR (bytes)

  // ---- prologue: stage Q tile (128x64, wave-private rows) into the union
#pragma unroll
  for (int r = 0; r < 4; ++r) {
    int c = w * 4 + r;                          // rows c*8..c*8+7 = wave-private
    async_cp16(Qb + (size_t)(b * 2048 + q0 + c * 8 + srow) * 1024 + h * 64 + scolX,
               (char*)SH + c * 1024);
  }
  // mask ints -> f32 additive bias (0 / -3e38), 8 entries/thread
  {
    const int* mp = mask + b * 2048 + tid * 8;
    int4 ma = *(const int4*)mp;
    int4 mb = *(const int4*)(mp + 4);
    float4 o0, o1;
    o0.x = ma.x ? -3.0e38f : 0.f; o0.y = ma.y ? -3.0e38f : 0.f;
    o0.z = ma.z ? -3.0e38f : 0.f; o0.w = ma.w ? -3.0e38f : 0.f;
    o1.x = mb.x ? -3.0e38f : 0.f; o1.y = mb.y ? -3.0e38f : 0.f;
    o1.z = mb.z ? -3.0e38f : 0.f; o1.w = mb.w ? -3.0e38f : 0.f;
    *(float4*)(Msf + tid * 8)     = o0;
    *(float4*)(Msf + tid * 8 + 4) = o1;
  }
  __syncthreads();   // drains Q cp16 (vmcnt(0)); Msf visible

  // Q fragments in registers (swizzled read); valid as B-operand of S^T
  bf16x8 aq[2][2];
#pragma unroll
  for (int i = 0; i < 2; ++i)
#pragma unroll
    for (int ks = 0; ks < 2; ++ks)
      aq[i][ks] = *(const bf16x8*)(const void*)(
          (const char*)SH + (w * 32 + i * 16 + l15) * 128 + (((ks * 4 + quad) << 4) ^ fsw));
  __syncthreads();   // all waves done reading Q before K/V overwrites the union

  // stage K/V tile 0 into buf 0
#pragma unroll
  for (int r = 0; r < 2; ++r) {
    int c = w * 2 + r;
    async_cp16(Kb + (size_t)(b * 2048 + c * 8 + srow) * 1024 + h * 64 + scolX,
               (char*)SH + c * 1024);                       // Ks0
    async_cp16(Vt + ((size_t)(b * 16 + h) * 64 + c * 8 + srow) * 2048 + scolX,
               (char*)SH + 16384 + c * 1024);               // Vs0
  }
  __syncthreads();   // tile 0 landed

  const f32x4 fz = {0.f, 0.f, 0.f, 0.f};
  f32x4 o[4][2];                        // O^T accum: [d-tile][q-tile]
  float rs[2] = {0.f, 0.f};             // per-lane partial row sums (quad-partitioned kk)
#pragma unroll
  for (int dt = 0; dt < 4; ++dt)
#pragma unroll
    for (int i = 0; i < 2; ++i) o[dt][i] = fz;

  int cur = 0;
  for (int kt = 0; kt < 2048; kt += 64) {
    const char* Kc = (const char*)SH + cur * 8192;
    const char* Vc = (const char*)SH + 16384 + cur * 8192;
    // issue next tile's loads into the other buffer (overlaps with compute)
    if (kt + 64 < 2048) {
      char* Kn = (char*)SH + (cur ^ 1) * 8192;
      char* Vn = (char*)SH + 16384 + (cur ^ 1) * 8192;
#pragma unroll
      for (int r = 0; r < 2; ++r) {
        int c = w * 2 + r;
        async_cp16(Kb + (size_t)(b * 2048 + kt + 64 + c * 8 + srow) * 1024 + h * 64 + scolX,
                   Kn + c * 1024);
        async_cp16(Vt + ((size_t)(b * 16 + h) * 64 + c * 8 + srow) * 2048 + kt + 64 + scolX,
                   Vn + c * 1024);
      }
    }

    bf16x8 kb[4][2];                    // K A-frags: m=kk=l15, k=d (swizzled read)
#pragma unroll
    for (int kkt = 0; kkt < 4; ++kkt)
#pragma unroll
      for (int ks = 0; ks < 2; ++ks)
        kb[kkt][ks] = *(const bf16x8*)(const void*)(
            Kc + (kkt * 16 + l15) * 128 + (((ks * 4 + quad) << 4) ^ fsw));

#pragma unroll
    for (int kkt = 0; kkt < 4; ++kkt) {
      f32x4 bias = *(const f32x4*)(Msf + kt + kkt * 16 + quad * 4);

      s16x4 pf[2];
#pragma unroll
      for (int i = 0; i < 2; ++i) {
        f32x4 st = MFMA32(kb[kkt][0], aq[i][0], bias);
        st = MFMA32(kb[kkt][1], aq[i][1], st);
        float p0 = EXP2(st[0]), p1 = EXP2(st[1]);
        float p2 = EXP2(st[2]), p3 = EXP2(st[3]);
        rs[i] += (p0 + p1) + (p2 + p3);
        union { unsigned u[2]; s16x4 s; } pk;
        pk.u[0] = cvt_pk(p0, p1);
        pk.u[1] = cvt_pk(p2, p3);
        pf[i] = pk.s;
      }
      __builtin_amdgcn_s_setprio(1);
#pragma unroll
      for (int dt = 0; dt < 4; ++dt) {
        s16x4 va = *(const s16x4*)(const void*)(
            Vc + (dt * 16 + l15) * 128 + ((kkt * 32 + quad * 8) ^ fsw));
#pragma unroll
        for (int i = 0; i < 2; ++i)
          o[dt][i] = MFMA16(va, pf[i], o[dt][i]);
      }
      __builtin_amdgcn_s_setprio(0);
    }
    __syncthreads();   // next tile landed; all reads of cur done
    cur ^= 1;
  }

  // row sums: reduce the 4 quad-partitions
  float inv[2];
#pragma unroll
  for (int i = 0; i < 2; ++i) {
    float v = rs[i];
    v += __shfl_xor(v, 16, 64);
    v += __shfl_xor(v, 32, 64);
    inv[i] = 1.0f / v;
  }

  // epilogue: un-transpose O^T via wave-private swizzled LDS strip (4 KB/wave,
  // reusing the union region — safe after the final loop barrier)
  u16* strip = SH + w * 2048;
#pragma unroll
  for (int dt = 0; dt < 4; ++dt)
#pragma unroll
    for (int i = 0; i < 2; ++i) {
      union { unsigned u[2]; s16x4 s; } pk;
      pk.u[0] = cvt_pk(o[dt][i][0] * inv[i], o[dt][i][1] * inv[i]);
      pk.u[1] = cvt_pk(o[dt][i][2] * inv[i], o[dt][i][3] * inv[i]);
      *(s16x4*)(void*)((char*)strip + (i * 16 + l15) * 128 + ((dt * 32 + quad * 8) ^ fsw)) = pk.s;
    }
  // coalesced store: 8 lanes x 16B per q-row (swizzled strip read)
#pragma unroll
  for (int pass = 0; pass < 4; ++pass) {
    int row = pass * 8 + (lane >> 3), oct = lane & 7;
    int4 v = *(const int4*)(const void*)((const char*)strip + row * 128 + ((oct ^ (row & 7)) << 4));
    *(int4*)(Ob + (size_t)(b * 2048 + q0 + w * 32 + row) * 1024 + h * 64 + oct * 8) = v;
  }
}

// ---------- launch ----------
extern "C" void kernel_launch(void* const* d_in, const int* in_sizes, int n_in,
                              void* d_out, int out_size, void* d_ws, size_t ws_size,
                              hipStream_t stream) {
  const float* x    = (const float*)d_in[0];
  const float* ctx  = (const float*)d_in[1];
  const int*   mask = (const int*)d_in[2];
  const float* lnqw = (const float*)d_in[3];
  const float* lnqb = (const float*)d_in[4];
  const float* lncw = (const float*)d_in[5];
  const float* lncb = (const float*)d_in[6];
  const float* Wq   = (const float*)d_in[7];
  const float* Wk   = (const float*)d_in[8];
  const float* Wv   = (const float*)d_in[9];
  const float* Wo   = (const float*)d_in[10];
  const float* tau  = (const float*)d_in[11];
  float* out = (float*)d_out;
  char* ws = (char*)d_ws;
  const size_t MB = 1024 * 1024;

  u16* qin  = (u16*)(ws + 0 * MB);    // 16 MB; reused as attn-out later
  u16* kvin = (u16*)(ws + 16 * MB);   // 16 MB
  u16* WqT  = (u16*)(ws + 32 * MB);   // 2 MB each
  u16* WkT  = (u16*)(ws + 34 * MB);
  u16* WvT  = (u16*)(ws + 36 * MB);
  u16* WoT  = (u16*)(ws + 38 * MB);
  u16* qbf  = (u16*)(ws + 40 * MB);   // 16 MB
  u16* kbf  = (u16*)(ws + 56 * MB);   // 16 MB
  u16* vT   = (u16*)(ws + 72 * MB);   // 16 MB  (total 88 MB — proven footprint)
  u16* attn = qin;                    // qin dead after gemm_qkv

  ln_cast2<<<16384, 256, 0, stream>>>(x, ctx, lnqw, lnqb, lncw, lncb, qin, kvin);
  wtrans4<<<dim3(16, 16, 4), 256, 0, stream>>>(Wq, Wk, Wv, Wo, WqT, WkT, WvT, WoT);

  gemm_qkv<<<dim3(8, 64, 3), 256, 0, stream>>>(qin, kvin, WqT, WkT, WvT,
                                               qbf, kbf, vT, tau);

  flash_attn10<<<dim3(16, 16, 4), 256, 0, stream>>>(qbf, kbf, vT, mask, attn);

  gemm_bt<<<dim3(8, 64), 256, 0, stream>>>(attn, WoT, out, 8192, 1024, 1024);
}

// Round 9
// 325.764 us; speedup vs baseline: 1.0344x; 1.0344x over previous
//
#include <hip/hip_runtime.h>

typedef unsigned short u16;
typedef __bf16 bf16x8 __attribute__((ext_vector_type(8)));
typedef short s16x4 __attribute__((ext_vector_type(4)));
typedef float f32x4 __attribute__((ext_vector_type(4)));

// ---------- helpers ----------
__device__ __forceinline__ u16 f2bf(float f) {
  unsigned u = __float_as_uint(f);
  unsigned r = u + 0x7fffu + ((u >> 16) & 1u);   // RNE
  return (u16)(r >> 16);
}

// two f32 -> packed bf16 dword in ONE instruction (low16 = a, high16 = b)
__device__ __forceinline__ unsigned cvt_pk(float a, float b) {
  unsigned r;
  asm("v_cvt_pk_bf16_f32 %0, %1, %2" : "=v"(r) : "v"(a), "v"(b));
  return r;
}

// exp2 via the builtin (raw v_exp_f32 WITH correct TRANS hazard modeling).
// R4 lesson: inline-asm v_exp_f32 loses the TRANS hazard nops -> NaN.
// R5 lesson: this swap alone was -30us on flash (exp2f lowers to OCML wrapper).
#if __has_builtin(__builtin_amdgcn_exp2f)
#define EXP2(x) __builtin_amdgcn_exp2f(x)
#else
#define EXP2(x) exp2f(x)
#endif

__device__ __forceinline__ void async_cp16(const void* g, void* l) {
  __builtin_amdgcn_global_load_lds((__attribute__((address_space(1))) void*)g,
                                   (__attribute__((address_space(3))) void*)l,
                                   16, 0, 0);
}

#define MFMA32(a, b, c) __builtin_amdgcn_mfma_f32_16x16x32_bf16(a, b, c, 0, 0, 0)

#if __has_builtin(__builtin_amdgcn_mfma_f32_16x16x16bf16_1k)
#define MFMA16(a, b, c) __builtin_amdgcn_mfma_f32_16x16x16bf16_1k(a, b, c, 0, 0, 0)
#else
__device__ __forceinline__ f32x4 mfma16_fb(s16x4 a, s16x4 b, f32x4 c) {
  asm("v_mfma_f32_16x16x16_bf16 %0, %1, %2, %0" : "+v"(c) : "v"(a), "v"(b));
  return c;
}
#define MFMA16(a, b, c) mfma16_fb(a, b, c)
#endif

// ---------- fused LayerNorm + bf16 cast (x and ctx in one dispatch) ----------
__global__ __launch_bounds__(256)
void ln_cast2(const float* __restrict__ X0, const float* __restrict__ X1,
              const float* __restrict__ W0, const float* __restrict__ B0,
              const float* __restrict__ W1, const float* __restrict__ B1,
              u16* __restrict__ Y0, u16* __restrict__ Y1) {
  __shared__ float red[8];
  const int blk = blockIdx.x, t = threadIdx.x;
  const int sel = blk >> 13;            // 0: x->qin, 1: ctx->kvin
  const int row = blk & 8191;
  const float* X = sel ? X1 : X0;
  const float* W = sel ? W1 : W0;
  const float* Bv = sel ? B1 : B0;
  u16* Y = sel ? Y1 : Y0;
  const int wave = t >> 6, lane = t & 63;
  const float4 v = ((const float4*)(X + (size_t)row * 1024))[t];
  float s  = v.x + v.y + v.z + v.w;
  float ss = v.x*v.x + v.y*v.y + v.z*v.z + v.w*v.w;
#pragma unroll
  for (int m = 32; m; m >>= 1) { s += __shfl_xor(s, m, 64); ss += __shfl_xor(ss, m, 64); }
  if (lane == 0) { red[wave] = s; red[4 + wave] = ss; }
  __syncthreads();
  float S  = red[0] + red[1] + red[2] + red[3];
  float SS = red[4] + red[5] + red[6] + red[7];
  float mu  = S * (1.0f / 1024.0f);
  float var = SS * (1.0f / 1024.0f) - mu * mu;
  float rstd = rsqrtf(var + 1e-5f);
  const float4 wv = ((const float4*)W)[t];
  const float4 bv = ((const float4*)Bv)[t];
  ushort4 o;
  o.x = f2bf((v.x - mu) * rstd * wv.x + bv.x);
  o.y = f2bf((v.y - mu) * rstd * wv.y + bv.y);
  o.z = f2bf((v.z - mu) * rstd * wv.z + bv.z);
  o.w = f2bf((v.w - mu) * rstd * wv.w + bv.w);
  ((ushort4*)(Y + (size_t)row * 1024))[t] = o;
}

// ---------- weight transpose + cast: all four W[K][N] f32 -> WT[N][K] bf16 ----------
__global__ __launch_bounds__(256)
void wtrans4(const float* __restrict__ Wq, const float* __restrict__ Wk,
             const float* __restrict__ Wv, const float* __restrict__ Wo,
             u16* __restrict__ WqT, u16* __restrict__ WkT,
             u16* __restrict__ WvT, u16* __restrict__ WoT) {
  __shared__ float t[64][65];
  const int z = blockIdx.z;
  const float* W = z == 0 ? Wq : (z == 1 ? Wk : (z == 2 ? Wv : Wo));
  u16* WT = z == 0 ? WqT : (z == 1 ? WkT : (z == 2 ? WvT : WoT));
  const int k0 = blockIdx.y * 64, n0 = blockIdx.x * 64;
  const int lr = threadIdx.x >> 4, lc = threadIdx.x & 15;
#pragma unroll
  for (int r = 0; r < 4; ++r) {
    int row = r * 16 + lr;
    float4 v = *(const float4*)(W + (size_t)(k0 + row) * 1024 + n0 + lc * 4);
    t[row][lc*4+0] = v.x; t[row][lc*4+1] = v.y; t[row][lc*4+2] = v.z; t[row][lc*4+3] = v.w;
  }
  __syncthreads();
#pragma unroll
  for (int r = 0; r < 4; ++r) {
    int n = r * 16 + lr;
    ushort4 o;
    o.x = f2bf(t[lc*4+0][n]); o.y = f2bf(t[lc*4+1][n]);
    o.z = f2bf(t[lc*4+2][n]); o.w = f2bf(t[lc*4+3][n]);
    *(ushort4*)(WT + (size_t)(n0 + n) * 1024 + k0 + lc * 4) = o;
  }
}

// ---------- fused Q/K/V projection GEMM (m97 structure, XCD-swizzled) ----------
// grid (512, 1, 3). XCD swizzle: blocks sharing an A m-panel (same y) all land
// on one XCD (ids congruent mod 8) -> A-panels (2MB) + B (2MB) fit its 4MB L2.
// z=0: qbf = l2n(qin x WqT, scaled);  z=1: kbf = l2n(kvin x WkT);
// z=2: vT = (kvin x WvT)^T directly as bf16 [b][h][d][kk].
__global__ __launch_bounds__(256, 2)
void gemm_qkv(const u16* __restrict__ qin, const u16* __restrict__ kvin,
              const u16* __restrict__ WqT, const u16* __restrict__ WkT,
              const u16* __restrict__ WvT,
              u16* __restrict__ qbf, u16* __restrict__ kbf,
              u16* __restrict__ vT, const float* __restrict__ taup) {
  __shared__ __align__(16) u16 shbuf[128 * 128];   // As | Bs staging; reused as transpose tile
  u16* As = shbuf;                                  // 128*64
  u16* Bs = shbuf + 128 * 64;                       // 128*64
  const int z = blockIdx.z;
  const u16* A  = z == 0 ? qin : kvin;
  const u16* Bt = z == 0 ? WqT : (z == 1 ? WkT : WvT);
  // XCD-aware remap: j%8 = XCD (512%8==0 so z doesn't shift it)
  const int j = blockIdx.x;
  const int xcd = j & 7, tt = j >> 3;               // tt 0..63
  const int ytile = xcd * 8 + (tt & 7);             // m-tile 0..63, 8 per XCD
  const int xtile = tt >> 3;                        // n-tile 0..7
  const int tid = threadIdx.x;
  const int wave = tid >> 6, lane = tid & 63;
  const int quad = lane >> 4, l15 = lane & 15;
  const int m0 = ytile * 128, n0 = xtile * 128;
  const int wm = (wave >> 1) * 64, wn = (wave & 1) * 64;
  const int srow = lane >> 3, scol = (lane & 7) * 8;
  const int K = 1024, N = 1024;

  const f32x4 fz = {0.f, 0.f, 0.f, 0.f};
  f32x4 acc[4][4];
#pragma unroll
  for (int i = 0; i < 4; ++i)
#pragma unroll
    for (int j2 = 0; j2 < 4; ++j2) acc[i][j2] = fz;

  for (int kt = 0; kt < K; kt += 64) {
    __syncthreads();
#pragma unroll
    for (int r = 0; r < 4; ++r) {
      const int c = r * 4 + wave;
      const int row = c * 8 + srow;
      async_cp16(A  + (size_t)(m0 + row) * K + kt + scol, (char*)As + c * 1024);
      async_cp16(Bt + (size_t)(n0 + row) * K + kt + scol, (char*)Bs + c * 1024);
    }
    __syncthreads();
#pragma unroll
    for (int ks = 0; ks < 2; ++ks) {
      bf16x8 af[4], bfr[4];
#pragma unroll
      for (int i = 0; i < 4; ++i)
        af[i] = *(const bf16x8*)(const void*)(As + (wm + i * 16 + l15) * 64 + ks * 32 + quad * 8);
#pragma unroll
      for (int j2 = 0; j2 < 4; ++j2)
        bfr[j2] = *(const bf16x8*)(const void*)(Bs + (wn + j2 * 16 + l15) * 64 + ks * 32 + quad * 8);
#pragma unroll
      for (int i = 0; i < 4; ++i)
#pragma unroll
        for (int j2 = 0; j2 < 4; ++j2)
          acc[i][j2] = MFMA32(af[i], bfr[j2], acc[i][j2]);
    }
  }

  if (z < 2) {
    // per-head l2norm epilogue -> bf16 (wave strip == one head)
    const float tsc = z == 0 ? 1.44269504f / (taup[0] + 1e-6f) : 1.0f;
    u16* Y = z == 0 ? qbf : kbf;
#pragma unroll
    for (int i = 0; i < 4; ++i)
#pragma unroll
      for (int e = 0; e < 4; ++e) {
        float ss = 0.f;
#pragma unroll
        for (int j2 = 0; j2 < 4; ++j2) ss = fmaf(acc[i][j2][e], acc[i][j2][e], ss);
        ss += __shfl_xor(ss, 1, 64); ss += __shfl_xor(ss, 2, 64);
        ss += __shfl_xor(ss, 4, 64); ss += __shfl_xor(ss, 8, 64);
        float sc = tsc / fmaxf(sqrtf(ss), 1e-12f);
        int row = m0 + wm + i * 16 + quad * 4 + e;
#pragma unroll
        for (int j2 = 0; j2 < 4; ++j2)
          Y[(size_t)row * N + n0 + wn + j2 * 16 + l15] = f2bf(acc[i][j2][e] * sc);
      }
  } else {
    // fused V-transpose epilogue: acc[kk_local][col_local] -> vT[b][h][d][kk] bf16.
    // LDS tile T[col][kk], XOR bank-swizzle: byte = col*256 + ((kk*2)^((col&7)<<4)).
    __syncthreads();                                   // As/Bs reads all done
    u16* T = shbuf;
#pragma unroll
    for (int i = 0; i < 4; ++i)
#pragma unroll
      for (int j2 = 0; j2 < 4; ++j2) {
        int col = wn + j2 * 16 + l15;
        int kkb = (wm + i * 16 + quad * 4) * 2;        // byte offset of 4 contiguous kk
        union { unsigned u[2]; s16x4 s; } pk;
        pk.u[0] = cvt_pk(acc[i][j2][0], acc[i][j2][1]);
        pk.u[1] = cvt_pk(acc[i][j2][2], acc[i][j2][3]);
        *(s16x4*)(void*)((char*)T + col * 256 + (kkb ^ ((col & 7) << 4))) = pk.s;
      }
    __syncthreads();
    // coalesced write: 2 threads per col, each streams 64 kk (8 x int4)
    const int bb = m0 >> 11, kk0 = m0 & 2047;
    const int col = tid >> 1, half = tid & 1;
    const int hh = (n0 + col) >> 6, d = (n0 + col) & 63;
    u16* dst = vT + ((size_t)(bb * 16 + hh) * 64 + d) * 2048 + kk0 + half * 64;
#pragma unroll
    for (int p = 0; p < 8; ++p) {
      int kkb = (half * 64 + p * 8) * 2;
      int4 v = *(const int4*)(const void*)((const char*)T + col * 256 + (kkb ^ ((col & 7) << 4)));
      *(int4*)(dst + p * 8) = v;
    }
  }
}

// ---------- GEMM C = A x Bt^T, M=8192 N=1024 K=1024, XCD-swizzled (grid 512) ----------
__global__ __launch_bounds__(256, 2)
void gemm_bt(const u16* __restrict__ A, const u16* __restrict__ Bt,
             float* __restrict__ C, int M, int N, int K) {
  __shared__ __align__(16) u16 As[128 * 64];
  __shared__ __align__(16) u16 Bs[128 * 64];
  const int j = blockIdx.x;
  const int xcd = j & 7, tt = j >> 3;
  const int ytile = xcd * 8 + (tt & 7);             // m-tile 0..63
  const int xtile = tt >> 3;                        // n-tile 0..7
  const int tid = threadIdx.x;
  const int wave = tid >> 6, lane = tid & 63;
  const int quad = lane >> 4, l15 = lane & 15;
  const int m0 = ytile * 128, n0 = xtile * 128;
  const int wm = (wave >> 1) * 64, wn = (wave & 1) * 64;
  const int srow = lane >> 3, scol = (lane & 7) * 8;

  const f32x4 fz = {0.f, 0.f, 0.f, 0.f};
  f32x4 acc[4][4];
#pragma unroll
  for (int i = 0; i < 4; ++i)
#pragma unroll
    for (int j2 = 0; j2 < 4; ++j2) acc[i][j2] = fz;

  for (int kt = 0; kt < K; kt += 64) {
    __syncthreads();
#pragma unroll
    for (int r = 0; r < 4; ++r) {
      const int c = r * 4 + wave;
      const int row = c * 8 + srow;
      async_cp16(A  + (size_t)(m0 + row) * K + kt + scol, (char*)As + c * 1024);
      async_cp16(Bt + (size_t)(n0 + row) * K + kt + scol, (char*)Bs + c * 1024);
    }
    __syncthreads();
#pragma unroll
    for (int ks = 0; ks < 2; ++ks) {
      bf16x8 af[4], bfr[4];
#pragma unroll
      for (int i = 0; i < 4; ++i)
        af[i] = *(const bf16x8*)(const void*)(As + (wm + i * 16 + l15) * 64 + ks * 32 + quad * 8);
#pragma unroll
      for (int j2 = 0; j2 < 4; ++j2)
        bfr[j2] = *(const bf16x8*)(const void*)(Bs + (wn + j2 * 16 + l15) * 64 + ks * 32 + quad * 8);
#pragma unroll
      for (int i = 0; i < 4; ++i)
#pragma unroll
        for (int j2 = 0; j2 < 4; ++j2)
          acc[i][j2] = MFMA32(af[i], bfr[j2], acc[i][j2]);
    }
  }
#pragma unroll
  for (int i = 0; i < 4; ++i)
#pragma unroll
    for (int j2 = 0; j2 < 4; ++j2)
#pragma unroll
      for (int e = 0; e < 4; ++e) {
        int row = m0 + wm + i * 16 + quad * 4 + e;
        int col = n0 + wn + j2 * 16 + l15;
        C[(size_t)row * N + col] = acc[i][j2][e];
      }
}

// ---------- flash attention v11: v10 + XCD-aware (b,h) clustering ----------
// grid 1024 (1-D). Each XCD owns 8 complete (b,h) K/V streams (16 q-tiles
// each, ids congruent mod 8) -> K/V fetched ~once per (b,h) instead of per
// XCD. Predicted FETCH 139MB -> ~60MB; shortens the staging drain tail.
__global__ __launch_bounds__(256, 2)
void flash_attn11(const u16* __restrict__ Qb, const u16* __restrict__ Kb,
                  const u16* __restrict__ Vt, const int* __restrict__ mask,
                  u16* __restrict__ Ob) {
  __shared__ __align__(16) u16 SH[16384];       // 32 KB union (Q stage / K,V dbuf / epilogue)
  __shared__ __align__(16) float Msf[2048];     // 8 KB mask bias f32: 0 or -3e38
  const int tid = threadIdx.x, w = tid >> 6, lane = tid & 63;
  const int quad = lane >> 4, l15 = lane & 15;
  // XCD swizzle: xcd = id%8 owns bh in [xcd*8, xcd*8+8)
  const int jb = blockIdx.x;
  const int xcd = jb & 7, slot = jb >> 3;       // slot 0..127
  const int bh = xcd * 8 + (slot >> 4);         // 0..63
  const int b = bh >> 4, h = bh & 15;
  const int q0 = (slot & 15) * 128;
  const int srow = lane >> 3;
  const int scolX = ((lane & 7) ^ srow) * 8;    // swizzled source column (u16 units)
  const int fsw = ((l15 & 7) << 4);             // read-side XOR (bytes)

  // ---- prologue: stage Q tile (128x64, wave-private rows) into the union
#pragma unroll
  for (int r = 0; r < 4; ++r) {
    int c = w * 4 + r;                          // rows c*8..c*8+7 = wave-private
    async_cp16(Qb + (size_t)(b * 2048 + q0 + c * 8 + srow) * 1024 + h * 64 + scolX,
               (char*)SH + c * 1024);
  }
  // mask ints -> f32 additive bias (0 / -3e38), 8 entries/thread
  {
    const int* mp = mask + b * 2048 + tid * 8;
    int4 ma = *(const int4*)mp;
    int4 mb = *(const int4*)(mp + 4);
    float4 o0, o1;
    o0.x = ma.x ? -3.0e38f : 0.f; o0.y = ma.y ? -3.0e38f : 0.f;
    o0.z = ma.z ? -3.0e38f : 0.f; o0.w = ma.w ? -3.0e38f : 0.f;
    o1.x = mb.x ? -3.0e38f : 0.f; o1.y = mb.y ? -3.0e38f : 0.f;
    o1.z = mb.z ? -3.0e38f : 0.f; o1.w = mb.w ? -3.0e38f : 0.f;
    *(float4*)(Msf + tid * 8)     = o0;
    *(float4*)(Msf + tid * 8 + 4) = o1;
  }
  __syncthreads();   // drains Q cp16 (vmcnt(0)); Msf visible

  // Q fragments in registers (swizzled read); valid as B-operand of S^T
  bf16x8 aq[2][2];
#pragma unroll
  for (int i = 0; i < 2; ++i)
#pragma unroll
    for (int ks = 0; ks < 2; ++ks)
      aq[i][ks] = *(const bf16x8*)(const void*)(
          (const char*)SH + (w * 32 + i * 16 + l15) * 128 + (((ks * 4 + quad) << 4) ^ fsw));
  __syncthreads();   // all waves done reading Q before K/V overwrites the union

  // stage K/V tile 0 into buf 0
#pragma unroll
  for (int r = 0; r < 2; ++r) {
    int c = w * 2 + r;
    async_cp16(Kb + (size_t)(b * 2048 + c * 8 + srow) * 1024 + h * 64 + scolX,
               (char*)SH + c * 1024);                       // Ks0
    async_cp16(Vt + ((size_t)(b * 16 + h) * 64 + c * 8 + srow) * 2048 + scolX,
               (char*)SH + 16384 + c * 1024);               // Vs0
  }
  __syncthreads();   // tile 0 landed

  const f32x4 fz = {0.f, 0.f, 0.f, 0.f};
  f32x4 o[4][2];                        // O^T accum: [d-tile][q-tile]
  float rs[2] = {0.f, 0.f};             // per-lane partial row sums (quad-partitioned kk)
#pragma unroll
  for (int dt = 0; dt < 4; ++dt)
#pragma unroll
    for (int i = 0; i < 2; ++i) o[dt][i] = fz;

  int cur = 0;
  for (int kt = 0; kt < 2048; kt += 64) {
    const char* Kc = (const char*)SH + cur * 8192;
    const char* Vc = (const char*)SH + 16384 + cur * 8192;
    // issue next tile's loads into the other buffer (overlaps with compute)
    if (kt + 64 < 2048) {
      char* Kn = (char*)SH + (cur ^ 1) * 8192;
      char* Vn = (char*)SH + 16384 + (cur ^ 1) * 8192;
#pragma unroll
      for (int r = 0; r < 2; ++r) {
        int c = w * 2 + r;
        async_cp16(Kb + (size_t)(b * 2048 + kt + 64 + c * 8 + srow) * 1024 + h * 64 + scolX,
                   Kn + c * 1024);
        async_cp16(Vt + ((size_t)(b * 16 + h) * 64 + c * 8 + srow) * 2048 + kt + 64 + scolX,
                   Vn + c * 1024);
      }
    }

    bf16x8 kb[4][2];                    // K A-frags: m=kk=l15, k=d (swizzled read)
#pragma unroll
    for (int kkt = 0; kkt < 4; ++kkt)
#pragma unroll
      for (int ks = 0; ks < 2; ++ks)
        kb[kkt][ks] = *(const bf16x8*)(const void*)(
            Kc + (kkt * 16 + l15) * 128 + (((ks * 4 + quad) << 4) ^ fsw));

#pragma unroll
    for (int kkt = 0; kkt < 4; ++kkt) {
      f32x4 bias = *(const f32x4*)(Msf + kt + kkt * 16 + quad * 4);

      s16x4 pf[2];
#pragma unroll
      for (int i = 0; i < 2; ++i) {
        f32x4 st = MFMA32(kb[kkt][0], aq[i][0], bias);
        st = MFMA32(kb[kkt][1], aq[i][1], st);
        float p0 = EXP2(st[0]), p1 = EXP2(st[1]);
        float p2 = EXP2(st[2]), p3 = EXP2(st[3]);
        rs[i] += (p0 + p1) + (p2 + p3);
        union { unsigned u[2]; s16x4 s; } pk;
        pk.u[0] = cvt_pk(p0, p1);
        pk.u[1] = cvt_pk(p2, p3);
        pf[i] = pk.s;
      }
      __builtin_amdgcn_s_setprio(1);
#pragma unroll
      for (int dt = 0; dt < 4; ++dt) {
        s16x4 va = *(const s16x4*)(const void*)(
            Vc + (dt * 16 + l15) * 128 + ((kkt * 32 + quad * 8) ^ fsw));
#pragma unroll
        for (int i = 0; i < 2; ++i)
          o[dt][i] = MFMA16(va, pf[i], o[dt][i]);
      }
      __builtin_amdgcn_s_setprio(0);
    }
    __syncthreads();   // next tile landed; all reads of cur done
    cur ^= 1;
  }

  // row sums: reduce the 4 quad-partitions
  float inv[2];
#pragma unroll
  for (int i = 0; i < 2; ++i) {
    float v = rs[i];
    v += __shfl_xor(v, 16, 64);
    v += __shfl_xor(v, 32, 64);
    inv[i] = 1.0f / v;
  }

  // epilogue: un-transpose O^T via wave-private swizzled LDS strip (4 KB/wave,
  // reusing the union region — safe after the final loop barrier)
  u16* strip = SH + w * 2048;
#pragma unroll
  for (int dt = 0; dt < 4; ++dt)
#pragma unroll
    for (int i = 0; i < 2; ++i) {
      union { unsigned u[2]; s16x4 s; } pk;
      pk.u[0] = cvt_pk(o[dt][i][0] * inv[i], o[dt][i][1] * inv[i]);
      pk.u[1] = cvt_pk(o[dt][i][2] * inv[i], o[dt][i][3] * inv[i]);
      *(s16x4*)(void*)((char*)strip + (i * 16 + l15) * 128 + ((dt * 32 + quad * 8) ^ fsw)) = pk.s;
    }
  // coalesced store: 8 lanes x 16B per q-row (swizzled strip read)
#pragma unroll
  for (int pass = 0; pass < 4; ++pass) {
    int row = pass * 8 + (lane >> 3), oct = lane & 7;
    int4 v = *(const int4*)(const void*)((const char*)strip + row * 128 + ((oct ^ (row & 7)) << 4));
    *(int4*)(Ob + (size_t)(b * 2048 + q0 + w * 32 + row) * 1024 + h * 64 + oct * 8) = v;
  }
}

// ---------- launch ----------
extern "C" void kernel_launch(void* const* d_in, const int* in_sizes, int n_in,
                              void* d_out, int out_size, void* d_ws, size_t ws_size,
                              hipStream_t stream) {
  const float* x    = (const float*)d_in[0];
  const float* ctx  = (const float*)d_in[1];
  const int*   mask = (const int*)d_in[2];
  const float* lnqw = (const float*)d_in[3];
  const float* lnqb = (const float*)d_in[4];
  const float* lncw = (const float*)d_in[5];
  const float* lncb = (const float*)d_in[6];
  const float* Wq   = (const float*)d_in[7];
  const float* Wk   = (const float*)d_in[8];
  const float* Wv   = (const float*)d_in[9];
  const float* Wo   = (const float*)d_in[10];
  const float* tau  = (const float*)d_in[11];
  float* out = (float*)d_out;
  char* ws = (char*)d_ws;
  const size_t MB = 1024 * 1024;

  u16* qin  = (u16*)(ws + 0 * MB);    // 16 MB; reused as attn-out later
  u16* kvin = (u16*)(ws + 16 * MB);   // 16 MB
  u16* WqT  = (u16*)(ws + 32 * MB);   // 2 MB each
  u16* WkT  = (u16*)(ws + 34 * MB);
  u16* WvT  = (u16*)(ws + 36 * MB);
  u16* WoT  = (u16*)(ws + 38 * MB);
  u16* qbf  = (u16*)(ws + 40 * MB);   // 16 MB
  u16* kbf  = (u16*)(ws + 56 * MB);   // 16 MB
  u16* vT   = (u16*)(ws + 72 * MB);   // 16 MB  (total 88 MB — proven footprint)
  u16* attn = qin;                    // qin dead after gemm_qkv

  ln_cast2<<<16384, 256, 0, stream>>>(x, ctx, lnqw, lnqb, lncw, lncb, qin, kvin);
  wtrans4<<<dim3(16, 16, 4), 256, 0, stream>>>(Wq, Wk, Wv, Wo, WqT, WkT, WvT, WoT);

  gemm_qkv<<<dim3(512, 1, 3), 256, 0, stream>>>(qin, kvin, WqT, WkT, WvT,
                                                qbf, kbf, vT, tau);

  flash_attn11<<<1024, 256, 0, stream>>>(qbf, kbf, vT, mask, attn);

  gemm_bt<<<512, 256, 0, stream>>>(attn, WoT, out, 8192, 1024, 1024);
}

// Round 10
// 322.803 us; speedup vs baseline: 1.0439x; 1.0092x over previous
//
#include <hip/hip_runtime.h>

typedef unsigned short u16;
typedef __bf16 bf16x8 __attribute__((ext_vector_type(8)));
typedef short s16x4 __attribute__((ext_vector_type(4)));
typedef float f32x4 __attribute__((ext_vector_type(4)));

// ---------- helpers ----------
__device__ __forceinline__ u16 f2bf(float f) {
  unsigned u = __float_as_uint(f);
  unsigned r = u + 0x7fffu + ((u >> 16) & 1u);   // RNE
  return (u16)(r >> 16);
}

// two f32 -> packed bf16 dword in ONE instruction (low16 = a, high16 = b)
__device__ __forceinline__ unsigned cvt_pk(float a, float b) {
  unsigned r;
  asm("v_cvt_pk_bf16_f32 %0, %1, %2" : "=v"(r) : "v"(a), "v"(b));
  return r;
}

// exp2 via the builtin (raw v_exp_f32 WITH correct TRANS hazard modeling).
// R4 lesson: inline-asm v_exp_f32 loses the TRANS hazard nops -> NaN.
// R5 lesson: this swap alone was -30us on flash (exp2f lowers to OCML wrapper).
#if __has_builtin(__builtin_amdgcn_exp2f)
#define EXP2(x) __builtin_amdgcn_exp2f(x)
#else
#define EXP2(x) exp2f(x)
#endif

__device__ __forceinline__ void async_cp16(const void* g, void* l) {
  __builtin_amdgcn_global_load_lds((__attribute__((address_space(1))) void*)g,
                                   (__attribute__((address_space(3))) void*)l,
                                   16, 0, 0);
}

#define MFMA32(a, b, c) __builtin_amdgcn_mfma_f32_16x16x32_bf16(a, b, c, 0, 0, 0)

#if __has_builtin(__builtin_amdgcn_mfma_f32_16x16x16bf16_1k)
#define MFMA16(a, b, c) __builtin_amdgcn_mfma_f32_16x16x16bf16_1k(a, b, c, 0, 0, 0)
#else
__device__ __forceinline__ f32x4 mfma16_fb(s16x4 a, s16x4 b, f32x4 c) {
  asm("v_mfma_f32_16x16x16_bf16 %0, %1, %2, %0" : "+v"(c) : "v"(a), "v"(b));
  return c;
}
#define MFMA16(a, b, c) mfma16_fb(a, b, c)
#endif

// ---------- fused prep: LayerNorm (x, ctx) + all four weight transposes ----------
// blocks [0,16384): ln rows; blocks [16384,17408): wtrans tiles.
__global__ __launch_bounds__(256)
void prep(const float* __restrict__ X0, const float* __restrict__ X1,
          const float* __restrict__ W0, const float* __restrict__ B0,
          const float* __restrict__ W1, const float* __restrict__ B1,
          u16* __restrict__ Y0, u16* __restrict__ Y1,
          const float* __restrict__ Wq, const float* __restrict__ Wk,
          const float* __restrict__ Wv, const float* __restrict__ Wo,
          u16* __restrict__ WqT, u16* __restrict__ WkT,
          u16* __restrict__ WvT, u16* __restrict__ WoT) {
  __shared__ float red[8];
  __shared__ float t[64][65];
  const int blk = blockIdx.x, tix = threadIdx.x;
  if (blk < 16384) {
    const int sel = blk >> 13;            // 0: x->qin, 1: ctx->kvin
    const int row = blk & 8191;
    const float* X = sel ? X1 : X0;
    const float* W = sel ? W1 : W0;
    const float* Bv = sel ? B1 : B0;
    u16* Y = sel ? Y1 : Y0;
    const int wave = tix >> 6, lane = tix & 63;
    const float4 v = ((const float4*)(X + (size_t)row * 1024))[tix];
    float s  = v.x + v.y + v.z + v.w;
    float ss = v.x*v.x + v.y*v.y + v.z*v.z + v.w*v.w;
#pragma unroll
    for (int m = 32; m; m >>= 1) { s += __shfl_xor(s, m, 64); ss += __shfl_xor(ss, m, 64); }
    if (lane == 0) { red[wave] = s; red[4 + wave] = ss; }
    __syncthreads();
    float S  = red[0] + red[1] + red[2] + red[3];
    float SS = red[4] + red[5] + red[6] + red[7];
    float mu  = S * (1.0f / 1024.0f);
    float var = SS * (1.0f / 1024.0f) - mu * mu;
    float rstd = rsqrtf(var + 1e-5f);
    const float4 wv = ((const float4*)W)[tix];
    const float4 bv = ((const float4*)Bv)[tix];
    ushort4 o;
    o.x = f2bf((v.x - mu) * rstd * wv.x + bv.x);
    o.y = f2bf((v.y - mu) * rstd * wv.y + bv.y);
    o.z = f2bf((v.z - mu) * rstd * wv.z + bv.z);
    o.w = f2bf((v.w - mu) * rstd * wv.w + bv.w);
    ((ushort4*)(Y + (size_t)row * 1024))[tix] = o;
  } else {
    const int id = blk - 16384;           // 0..1023
    const int z = id >> 8, yy = (id >> 4) & 15, xx = id & 15;
    const float* W = z == 0 ? Wq : (z == 1 ? Wk : (z == 2 ? Wv : Wo));
    u16* WT = z == 0 ? WqT : (z == 1 ? WkT : (z == 2 ? WvT : WoT));
    const int k0 = yy * 64, n0 = xx * 64;
    const int lr = tix >> 4, lc = tix & 15;
#pragma unroll
    for (int r = 0; r < 4; ++r) {
      int row = r * 16 + lr;
      float4 v = *(const float4*)(W + (size_t)(k0 + row) * 1024 + n0 + lc * 4);
      t[row][lc*4+0] = v.x; t[row][lc*4+1] = v.y; t[row][lc*4+2] = v.z; t[row][lc*4+3] = v.w;
    }
    __syncthreads();
#pragma unroll
    for (int r = 0; r < 4; ++r) {
      int n = r * 16 + lr;
      ushort4 o;
      o.x = f2bf(t[lc*4+0][n]); o.y = f2bf(t[lc*4+1][n]);
      o.z = f2bf(t[lc*4+2][n]); o.w = f2bf(t[lc*4+3][n]);
      *(ushort4*)(WT + (size_t)(n0 + n) * 1024 + k0 + lc * 4) = o;
    }
  }
}

// ---------- fused Q/K/V projection GEMM (m97 structure, XCD-swizzled) ----------
// grid (512, 1, 3). XCD swizzle: blocks sharing an A m-panel (same y) all land
// on one XCD (ids congruent mod 8) -> A-panels (2MB) + B (2MB) fit its 4MB L2.
// z=0: qbf = l2n(qin x WqT, scaled);  z=1: kbf = l2n(kvin x WkT);
// z=2: vT = (kvin x WvT)^T directly as bf16 [b][h][d][kk].
__global__ __launch_bounds__(256, 2)
void gemm_qkv(const u16* __restrict__ qin, const u16* __restrict__ kvin,
              const u16* __restrict__ WqT, const u16* __restrict__ WkT,
              const u16* __restrict__ WvT,
              u16* __restrict__ qbf, u16* __restrict__ kbf,
              u16* __restrict__ vT, const float* __restrict__ taup) {
  __shared__ __align__(16) u16 shbuf[128 * 128];   // As | Bs staging; reused as transpose tile
  u16* As = shbuf;                                  // 128*64
  u16* Bs = shbuf + 128 * 64;                       // 128*64
  const int z = blockIdx.z;
  const u16* A  = z == 0 ? qin : kvin;
  const u16* Bt = z == 0 ? WqT : (z == 1 ? WkT : WvT);
  // XCD-aware remap: j%8 = XCD (512%8==0 so z doesn't shift it)
  const int j = blockIdx.x;
  const int xcd = j & 7, tt = j >> 3;               // tt 0..63
  const int ytile = xcd * 8 + (tt & 7);             // m-tile 0..63, 8 per XCD
  const int xtile = tt >> 3;                        // n-tile 0..7
  const int tid = threadIdx.x;
  const int wave = tid >> 6, lane = tid & 63;
  const int quad = lane >> 4, l15 = lane & 15;
  const int m0 = ytile * 128, n0 = xtile * 128;
  const int wm = (wave >> 1) * 64, wn = (wave & 1) * 64;
  const int srow = lane >> 3, scol = (lane & 7) * 8;
  const int K = 1024, N = 1024;

  const f32x4 fz = {0.f, 0.f, 0.f, 0.f};
  f32x4 acc[4][4];
#pragma unroll
  for (int i = 0; i < 4; ++i)
#pragma unroll
    for (int j2 = 0; j2 < 4; ++j2) acc[i][j2] = fz;

  for (int kt = 0; kt < K; kt += 64) {
    __syncthreads();
#pragma unroll
    for (int r = 0; r < 4; ++r) {
      const int c = r * 4 + wave;
      const int row = c * 8 + srow;
      async_cp16(A  + (size_t)(m0 + row) * K + kt + scol, (char*)As + c * 1024);
      async_cp16(Bt + (size_t)(n0 + row) * K + kt + scol, (char*)Bs + c * 1024);
    }
    __syncthreads();
#pragma unroll
    for (int ks = 0; ks < 2; ++ks) {
      bf16x8 af[4], bfr[4];
#pragma unroll
      for (int i = 0; i < 4; ++i)
        af[i] = *(const bf16x8*)(const void*)(As + (wm + i * 16 + l15) * 64 + ks * 32 + quad * 8);
#pragma unroll
      for (int j2 = 0; j2 < 4; ++j2)
        bfr[j2] = *(const bf16x8*)(const void*)(Bs + (wn + j2 * 16 + l15) * 64 + ks * 32 + quad * 8);
#pragma unroll
      for (int i = 0; i < 4; ++i)
#pragma unroll
        for (int j2 = 0; j2 < 4; ++j2)
          acc[i][j2] = MFMA32(af[i], bfr[j2], acc[i][j2]);
    }
  }

  if (z < 2) {
    // per-head l2norm epilogue -> bf16 (wave strip == one head)
    const float tsc = z == 0 ? 1.44269504f / (taup[0] + 1e-6f) : 1.0f;
    u16* Y = z == 0 ? qbf : kbf;
#pragma unroll
    for (int i = 0; i < 4; ++i)
#pragma unroll
      for (int e = 0; e < 4; ++e) {
        float ss = 0.f;
#pragma unroll
        for (int j2 = 0; j2 < 4; ++j2) ss = fmaf(acc[i][j2][e], acc[i][j2][e], ss);
        ss += __shfl_xor(ss, 1, 64); ss += __shfl_xor(ss, 2, 64);
        ss += __shfl_xor(ss, 4, 64); ss += __shfl_xor(ss, 8, 64);
        float sc = tsc / fmaxf(sqrtf(ss), 1e-12f);
        int row = m0 + wm + i * 16 + quad * 4 + e;
#pragma unroll
        for (int j2 = 0; j2 < 4; ++j2)
          Y[(size_t)row * N + n0 + wn + j2 * 16 + l15] = f2bf(acc[i][j2][e] * sc);
      }
  } else {
    // fused V-transpose epilogue: acc[kk_local][col_local] -> vT[b][h][d][kk] bf16.
    // LDS tile T[col][kk], XOR bank-swizzle: byte = col*256 + ((kk*2)^((col&7)<<4)).
    __syncthreads();                                   // As/Bs reads all done
    u16* T = shbuf;
#pragma unroll
    for (int i = 0; i < 4; ++i)
#pragma unroll
      for (int j2 = 0; j2 < 4; ++j2) {
        int col = wn + j2 * 16 + l15;
        int kkb = (wm + i * 16 + quad * 4) * 2;        // byte offset of 4 contiguous kk
        union { unsigned u[2]; s16x4 s; } pk;
        pk.u[0] = cvt_pk(acc[i][j2][0], acc[i][j2][1]);
        pk.u[1] = cvt_pk(acc[i][j2][2], acc[i][j2][3]);
        *(s16x4*)(void*)((char*)T + col * 256 + (kkb ^ ((col & 7) << 4))) = pk.s;
      }
    __syncthreads();
    // coalesced write: 2 threads per col, each streams 64 kk (8 x int4)
    const int bb = m0 >> 11, kk0 = m0 & 2047;
    const int col = tid >> 1, half = tid & 1;
    const int hh = (n0 + col) >> 6, d = (n0 + col) & 63;
    u16* dst = vT + ((size_t)(bb * 16 + hh) * 64 + d) * 2048 + kk0 + half * 64;
#pragma unroll
    for (int p = 0; p < 8; ++p) {
      int kkb = (half * 64 + p * 8) * 2;
      int4 v = *(const int4*)(const void*)((const char*)T + col * 256 + (kkb ^ ((col & 7) << 4)));
      *(int4*)(dst + p * 8) = v;
    }
  }
}

// ---------- GEMM C = A x Bt^T, M=8192 N=1024 K=1024, XCD-swizzled (grid 512) ----------
__global__ __launch_bounds__(256, 2)
void gemm_bt(const u16* __restrict__ A, const u16* __restrict__ Bt,
             float* __restrict__ C, int M, int N, int K) {
  __shared__ __align__(16) u16 As[128 * 64];
  __shared__ __align__(16) u16 Bs[128 * 64];
  const int j = blockIdx.x;
  const int xcd = j & 7, tt = j >> 3;
  const int ytile = xcd * 8 + (tt & 7);             // m-tile 0..63
  const int xtile = tt >> 3;                        // n-tile 0..7
  const int tid = threadIdx.x;
  const int wave = tid >> 6, lane = tid & 63;
  const int quad = lane >> 4, l15 = lane & 15;
  const int m0 = ytile * 128, n0 = xtile * 128;
  const int wm = (wave >> 1) * 64, wn = (wave & 1) * 64;
  const int srow = lane >> 3, scol = (lane & 7) * 8;

  const f32x4 fz = {0.f, 0.f, 0.f, 0.f};
  f32x4 acc[4][4];
#pragma unroll
  for (int i = 0; i < 4; ++i)
#pragma unroll
    for (int j2 = 0; j2 < 4; ++j2) acc[i][j2] = fz;

  for (int kt = 0; kt < K; kt += 64) {
    __syncthreads();
#pragma unroll
    for (int r = 0; r < 4; ++r) {
      const int c = r * 4 + wave;
      const int row = c * 8 + srow;
      async_cp16(A  + (size_t)(m0 + row) * K + kt + scol, (char*)As + c * 1024);
      async_cp16(Bt + (size_t)(n0 + row) * K + kt + scol, (char*)Bs + c * 1024);
    }
    __syncthreads();
#pragma unroll
    for (int ks = 0; ks < 2; ++ks) {
      bf16x8 af[4], bfr[4];
#pragma unroll
      for (int i = 0; i < 4; ++i)
        af[i] = *(const bf16x8*)(const void*)(As + (wm + i * 16 + l15) * 64 + ks * 32 + quad * 8);
#pragma unroll
      for (int j2 = 0; j2 < 4; ++j2)
        bfr[j2] = *(const bf16x8*)(const void*)(Bs + (wn + j2 * 16 + l15) * 64 + ks * 32 + quad * 8);
#pragma unroll
      for (int i = 0; i < 4; ++i)
#pragma unroll
        for (int j2 = 0; j2 < 4; ++j2)
          acc[i][j2] = MFMA32(af[i], bfr[j2], acc[i][j2]);
    }
  }
#pragma unroll
  for (int i = 0; i < 4; ++i)
#pragma unroll
    for (int j2 = 0; j2 < 4; ++j2)
#pragma unroll
      for (int e = 0; e < 4; ++e) {
        int row = m0 + wm + i * 16 + quad * 4 + e;
        int col = n0 + wn + j2 * 16 + l15;
        C[(size_t)row * N + col] = acc[i][j2][e];
      }
}

// ---------- flash attention v12: v11 with bf16 mask bias -> LDS 36864 ----------
// R9 lesson: flash is issue-bound (HBM 5%) and was at 3 blocks/CU (40960B x 4
// = exactly 163840 doesn't fit -> 1024 blocks ran as 768 + 256 tail).
// Shrinking the mask bias to bf16 (4KB, v6-proven unpack) gives 36864B x 4 =
// 147456 -> 4 blocks/CU, single balanced generation, zero tail.
__global__ __launch_bounds__(256, 2)
void flash_attn12(const u16* __restrict__ Qb, const u16* __restrict__ Kb,
                  const u16* __restrict__ Vt, const int* __restrict__ mask,
                  u16* __restrict__ Ob) {
  __shared__ __align__(16) u16 SH[16384];       // 32 KB union (Q stage / K,V dbuf / epilogue)
  __shared__ __align__(16) u16 Msb[2048];       // 4 KB mask bias bf16: 0 or 0xFF7F (-3.39e38)
  const int tid = threadIdx.x, w = tid >> 6, lane = tid & 63;
  const int quad = lane >> 4, l15 = lane & 15;
  // XCD swizzle: xcd = id%8 owns bh in [xcd*8, xcd*8+8)
  const int jb = blockIdx.x;
  const int xcd = jb & 7, slot = jb >> 3;       // slot 0..127
  const int bh = xcd * 8 + (slot >> 4);         // 0..63
  const int b = bh >> 4, h = bh & 15;
  const int q0 = (slot & 15) * 128;
  const int srow = lane >> 3;
  const int scolX = ((lane & 7) ^ srow) * 8;    // swizzled source column (u16 units)
  const int fsw = ((l15 & 7) << 4);             // read-side XOR (bytes)

  // ---- prologue: stage Q tile (128x64, wave-private rows) into the union
#pragma unroll
  for (int r = 0; r < 4; ++r) {
    int c = w * 4 + r;                          // rows c*8..c*8+7 = wave-private
    async_cp16(Qb + (size_t)(b * 2048 + q0 + c * 8 + srow) * 1024 + h * 64 + scolX,
               (char*)SH + c * 1024);
  }
  // mask ints -> bf16 additive bias (0 / -3.39e38), 8 entries/thread
  {
    const int* mp = mask + b * 2048 + tid * 8;
    int4 ma = *(const int4*)mp;
    int4 mb = *(const int4*)(mp + 4);
    ushort4 o0, o1;
    o0.x = ma.x ? 0xFF7Fu : 0u; o0.y = ma.y ? 0xFF7Fu : 0u;
    o0.z = ma.z ? 0xFF7Fu : 0u; o0.w = ma.w ? 0xFF7Fu : 0u;
    o1.x = mb.x ? 0xFF7Fu : 0u; o1.y = mb.y ? 0xFF7Fu : 0u;
    o1.z = mb.z ? 0xFF7Fu : 0u; o1.w = mb.w ? 0xFF7Fu : 0u;
    *(ushort4*)(Msb + tid * 8)     = o0;
    *(ushort4*)(Msb + tid * 8 + 4) = o1;
  }
  __syncthreads();   // drains Q cp16 (vmcnt(0)); Msb visible

  // Q fragments in registers (swizzled read); valid as B-operand of S^T
  bf16x8 aq[2][2];
#pragma unroll
  for (int i = 0; i < 2; ++i)
#pragma unroll
    for (int ks = 0; ks < 2; ++ks)
      aq[i][ks] = *(const bf16x8*)(const void*)(
          (const char*)SH + (w * 32 + i * 16 + l15) * 128 + (((ks * 4 + quad) << 4) ^ fsw));
  __syncthreads();   // all waves done reading Q before K/V overwrites the union

  // stage K/V tile 0 into buf 0
#pragma unroll
  for (int r = 0; r < 2; ++r) {
    int c = w * 2 + r;
    async_cp16(Kb + (size_t)(b * 2048 + c * 8 + srow) * 1024 + h * 64 + scolX,
               (char*)SH + c * 1024);                       // Ks0
    async_cp16(Vt + ((size_t)(b * 16 + h) * 64 + c * 8 + srow) * 2048 + scolX,
               (char*)SH + 16384 + c * 1024);               // Vs0
  }
  __syncthreads();   // tile 0 landed

  const f32x4 fz = {0.f, 0.f, 0.f, 0.f};
  f32x4 o[4][2];                        // O^T accum: [d-tile][q-tile]
  float rs[2] = {0.f, 0.f};             // per-lane partial row sums (quad-partitioned kk)
#pragma unroll
  for (int dt = 0; dt < 4; ++dt)
#pragma unroll
    for (int i = 0; i < 2; ++i) o[dt][i] = fz;

  int cur = 0;
  for (int kt = 0; kt < 2048; kt += 64) {
    const char* Kc = (const char*)SH + cur * 8192;
    const char* Vc = (const char*)SH + 16384 + cur * 8192;
    // issue next tile's loads into the other buffer (overlaps with compute)
    if (kt + 64 < 2048) {
      char* Kn = (char*)SH + (cur ^ 1) * 8192;
      char* Vn = (char*)SH + 16384 + (cur ^ 1) * 8192;
#pragma unroll
      for (int r = 0; r < 2; ++r) {
        int c = w * 2 + r;
        async_cp16(Kb + (size_t)(b * 2048 + kt + 64 + c * 8 + srow) * 1024 + h * 64 + scolX,
                   Kn + c * 1024);
        async_cp16(Vt + ((size_t)(b * 16 + h) * 64 + c * 8 + srow) * 2048 + kt + 64 + scolX,
                   Vn + c * 1024);
      }
    }

    bf16x8 kb[4][2];                    // K A-frags: m=kk=l15, k=d (swizzled read)
#pragma unroll
    for (int kkt = 0; kkt < 4; ++kkt)
#pragma unroll
      for (int ks = 0; ks < 2; ++ks)
        kb[kkt][ks] = *(const bf16x8*)(const void*)(
            Kc + (kkt * 16 + l15) * 128 + (((ks * 4 + quad) << 4) ^ fsw));

#pragma unroll
    for (int kkt = 0; kkt < 4; ++kkt) {
      // additive bias for this lane's 4 kk rows (broadcast b64 read + unpack)
      s16x4 mbv = *(const s16x4*)(Msb + kt + kkt * 16 + quad * 4);
      f32x4 bias;
#pragma unroll
      for (int e = 0; e < 4; ++e)
        bias[e] = __uint_as_float(((unsigned)(u16)mbv[e]) << 16);

      s16x4 pf[2];
#pragma unroll
      for (int i = 0; i < 2; ++i) {
        f32x4 st = MFMA32(kb[kkt][0], aq[i][0], bias);
        st = MFMA32(kb[kkt][1], aq[i][1], st);
        float p0 = EXP2(st[0]), p1 = EXP2(st[1]);
        float p2 = EXP2(st[2]), p3 = EXP2(st[3]);
        rs[i] += (p0 + p1) + (p2 + p3);
        union { unsigned u[2]; s16x4 s; } pk;
        pk.u[0] = cvt_pk(p0, p1);
        pk.u[1] = cvt_pk(p2, p3);
        pf[i] = pk.s;
      }
      __builtin_amdgcn_s_setprio(1);
#pragma unroll
      for (int dt = 0; dt < 4; ++dt) {
        s16x4 va = *(const s16x4*)(const void*)(
            Vc + (dt * 16 + l15) * 128 + ((kkt * 32 + quad * 8) ^ fsw));
#pragma unroll
        for (int i = 0; i < 2; ++i)
          o[dt][i] = MFMA16(va, pf[i], o[dt][i]);
      }
      __builtin_amdgcn_s_setprio(0);
    }
    __syncthreads();   // next tile landed; all reads of cur done
    cur ^= 1;
  }

  // row sums: reduce the 4 quad-partitions
  float inv[2];
#pragma unroll
  for (int i = 0; i < 2; ++i) {
    float v = rs[i];
    v += __shfl_xor(v, 16, 64);
    v += __shfl_xor(v, 32, 64);
    inv[i] = 1.0f / v;
  }

  // epilogue: un-transpose O^T via wave-private swizzled LDS strip (4 KB/wave,
  // reusing the union region — safe after the final loop barrier)
  u16* strip = SH + w * 2048;
#pragma unroll
  for (int dt = 0; dt < 4; ++dt)
#pragma unroll
    for (int i = 0; i < 2; ++i) {
      union { unsigned u[2]; s16x4 s; } pk;
      pk.u[0] = cvt_pk(o[dt][i][0] * inv[i], o[dt][i][1] * inv[i]);
      pk.u[1] = cvt_pk(o[dt][i][2] * inv[i], o[dt][i][3] * inv[i]);
      *(s16x4*)(void*)((char*)strip + (i * 16 + l15) * 128 + ((dt * 32 + quad * 8) ^ fsw)) = pk.s;
    }
  // coalesced store: 8 lanes x 16B per q-row (swizzled strip read)
#pragma unroll
  for (int pass = 0; pass < 4; ++pass) {
    int row = pass * 8 + (lane >> 3), oct = lane & 7;
    int4 v = *(const int4*)(const void*)((const char*)strip + row * 128 + ((oct ^ (row & 7)) << 4));
    *(int4*)(Ob + (size_t)(b * 2048 + q0 + w * 32 + row) * 1024 + h * 64 + oct * 8) = v;
  }
}

// ---------- launch ----------
extern "C" void kernel_launch(void* const* d_in, const int* in_sizes, int n_in,
                              void* d_out, int out_size, void* d_ws, size_t ws_size,
                              hipStream_t stream) {
  const float* x    = (const float*)d_in[0];
  const float* ctx  = (const float*)d_in[1];
  const int*   mask = (const int*)d_in[2];
  const float* lnqw = (const float*)d_in[3];
  const float* lnqb = (const float*)d_in[4];
  const float* lncw = (const float*)d_in[5];
  const float* lncb = (const float*)d_in[6];
  const float* Wq   = (const float*)d_in[7];
  const float* Wk   = (const float*)d_in[8];
  const float* Wv   = (const float*)d_in[9];
  const float* Wo   = (const float*)d_in[10];
  const float* tau  = (const float*)d_in[11];
  float* out = (float*)d_out;
  char* ws = (char*)d_ws;
  const size_t MB = 1024 * 1024;

  u16* qin  = (u16*)(ws + 0 * MB);    // 16 MB; reused as attn-out later
  u16* kvin = (u16*)(ws + 16 * MB);   // 16 MB
  u16* WqT  = (u16*)(ws + 32 * MB);   // 2 MB each
  u16* WkT  = (u16*)(ws + 34 * MB);
  u16* WvT  = (u16*)(ws + 36 * MB);
  u16* WoT  = (u16*)(ws + 38 * MB);
  u16* qbf  = (u16*)(ws + 40 * MB);   // 16 MB
  u16* kbf  = (u16*)(ws + 56 * MB);   // 16 MB
  u16* vT   = (u16*)(ws + 72 * MB);   // 16 MB  (total 88 MB — proven footprint)
  u16* attn = qin;                    // qin dead after gemm_qkv

  prep<<<17408, 256, 0, stream>>>(x, ctx, lnqw, lnqb, lncw, lncb, qin, kvin,
                                  Wq, Wk, Wv, Wo, WqT, WkT, WvT, WoT);

  gemm_qkv<<<dim3(512, 1, 3), 256, 0, stream>>>(qin, kvin, WqT, WkT, WvT,
                                                qbf, kbf, vT, tau);

  flash_attn12<<<1024, 256, 0, stream>>>(qbf, kbf, vT, mask, attn);

  gemm_bt<<<512, 256, 0, stream>>>(attn, WoT, out, 8192, 1024, 1024);
}